// Round 8
// baseline (403.740 us; speedup 1.0000x reference)
//
#include <hip/hip_runtime.h>

// RNN: h_t = tanh(x_t * W_ih^T + b_ih + h_{t-1} W_hh^T + b_hh), out = h_T W_fc^T + b_fc
// B=8192, T=784, I=1, H=30 (pad 32), C=10. fp32.
//
// R10 = R9 body (proven: MFMA split-float + zero-shuffle permuted-A layout,
// absmax 2^-9) with the launch GEOMETRY fixed. R9 counters: 714 clk/step,
// VALU busy ~230, MFMA ~34 => ~450 clk/step dependency stall, because 512
// waves over 1024 SIMDs = 1 wave/SIMD (Occupancy 5.6%) -- the recurrence
// chain (tanh -> pack -> 3xMFMA) latency is fully exposed with no TLP.
// Fix: 512-thread workgroups (8 waves) -> each CU holds 8 waves on 4 SIMDs
// = 2 waves/SIMD on 64 CUs; wave B's issue fills wave A's stall windows.
// Expected step ~ max(2 x busy, chain) ~ 460-550 clk vs 714.
// (Idle CUs can't be used: batches/wave is fixed at 16 by MFMA N, and a
// hybrid VALU partition loses by arithmetic -- VALU = 111 clk/batch-step
// vs MFMA 29, the VALU part would finish last.)

#define BB 8192
#define TT 784
#define HH 30
#define CC 10

typedef __attribute__((ext_vector_type(8))) short  bf16x8;
typedef __attribute__((ext_vector_type(4))) float  f32x4;
typedef __attribute__((ext_vector_type(4))) unsigned uint4v;

__device__ __forceinline__ float tanh_fast(float a) {
    // identical numerics to R2..R9
    return 1.0f - 2.0f * __builtin_amdgcn_rcpf(__expf(2.0f * a) + 1.0f);
}

// (p0,p1) f32 -> packed bf16 pair hp (RNE) + packed bf16 residual pair lp.
#define BPAIR(p0, p1, hp, lp) do {                                          \
    asm("v_cvt_pk_bf16_f32 %0, %1, %2" : "=v"(hp) : "v"(p0), "v"(p1));      \
    const float _h0 = __uint_as_float((hp) << 16);                          \
    const float _h1 = __uint_as_float((hp) & 0xffff0000u);                  \
    const float _l0 = (p0) - _h0;                                           \
    const float _l1 = (p1) - _h1;                                           \
    asm("v_cvt_pk_bf16_f32 %0, %1, %2" : "=v"(lp) : "v"(_l0), "v"(_l1));    \
} while (0)

__global__ __launch_bounds__(512)
__attribute__((amdgpu_waves_per_eu(2, 2)))
void rnn_scan_kernel(const float* __restrict__ x,
                     const float* __restrict__ W_ih,
                     const float* __restrict__ W_hh,
                     const float* __restrict__ b_ih,
                     const float* __restrict__ b_hh,
                     const float* __restrict__ W_fc,
                     const float* __restrict__ b_fc,
                     float* __restrict__ out) {
    const int wv   = threadIdx.x >> 6;   // wave 0..7 within the workgroup
    const int lane = threadIdx.x & 63;
    const int n    = lane & 15;          // batch column (A row index too)
    const int g    = lane >> 4;          // k-group / D-row group
    const int b    = blockIdx.x * 128 + wv * 16 + n;

    // ---- A fragments: per-lane row n of each tile, k = 8g..8g+7 ----
    const int r1 = 8 * (n >> 2) + (n & 3);   // tile1 W-row, always <= 27
    const int r2 = r1 + 4;                    // tile2 W-row, 30/31 -> zero row
    unsigned a1h[4], a1l[4], a2h[4], a2l[4];
#pragma unroll
    for (int d = 0; d < 4; ++d) {
        const int k0 = 8 * g + 2 * d, k1 = k0 + 1;
        const float w1a = (k0 < HH) ? W_hh[r1 * HH + k0] : 0.f;
        const float w1b = (k1 < HH) ? W_hh[r1 * HH + k1] : 0.f;
        const float w2a = (r2 < HH && k0 < HH) ? W_hh[r2 * HH + k0] : 0.f;
        const float w2b = (r2 < HH && k1 < HH) ? W_hh[r2 * HH + k1] : 0.f;
        const unsigned u1a = __float_as_uint(w1a), u1b = __float_as_uint(w1b);
        const unsigned u2a = __float_as_uint(w2a), u2b = __float_as_uint(w2b);
        a1h[d] = (u1b & 0xffff0000u) | (u1a >> 16);
        a2h[d] = (u2b & 0xffff0000u) | (u2a >> 16);
        const float l1a = w1a - __uint_as_float(u1a & 0xffff0000u);
        const float l1b = w1b - __uint_as_float(u1b & 0xffff0000u);
        const float l2a = w2a - __uint_as_float(u2a & 0xffff0000u);
        const float l2b = w2b - __uint_as_float(u2b & 0xffff0000u);
        a1l[d] = (__float_as_uint(l1b) & 0xffff0000u) | (__float_as_uint(l1a) >> 16);
        a2l[d] = (__float_as_uint(l2b) & 0xffff0000u) | (__float_as_uint(l2a) >> 16);
    }
    bf16x8 A1h = __builtin_bit_cast(bf16x8, (uint4v){a1h[0], a1h[1], a1h[2], a1h[3]});
    bf16x8 A1l = __builtin_bit_cast(bf16x8, (uint4v){a1l[0], a1l[1], a1l[2], a1l[3]});
    bf16x8 A2h = __builtin_bit_cast(bf16x8, (uint4v){a2h[0], a2h[1], a2h[2], a2h[3]});
    bf16x8 A2l = __builtin_bit_cast(bf16x8, (uint4v){a2l[0], a2l[1], a2l[2], a2l[3]});
    // volatile pins: defs cannot be sunk into the loop (R4/R6 lesson)
    asm volatile("" : "+v"(A1h), "+v"(A1l), "+v"(A2h), "+v"(A2l));

    // ---- C-init params: D rows of this lane are h-rows 8g+r / 8g+4+r ----
    float bias1[4], wih1[4], bias2[4], wih2[4];
#pragma unroll
    for (int r = 0; r < 4; ++r) {
        const int q1 = 8 * g + r;                       // <= 27
        bias1[r] = b_ih[q1] + b_hh[q1];
        wih1[r]  = W_ih[q1];
        const int q2 = q1 + 4;                          // 30/31 -> zero
        bias2[r] = (q2 < HH) ? (b_ih[q2] + b_hh[q2]) : 0.f;
        wih2[r]  = (q2 < HH) ? W_ih[q2] : 0.f;
        asm volatile("" : "+v"(bias1[r]), "+v"(wih1[r]), "+v"(bias2[r]), "+v"(wih2[r]));
    }

    // h state: lane holds h[8g+j], j=0..7 (j<4 from tile1, j>=4 from tile2)
    float h0 = 0.f, h1 = 0.f, h2 = 0.f, h3 = 0.f;
    float h4 = 0.f, h5 = 0.f, h6 = 0.f, h7 = 0.f;

    const float* xp = x + (size_t)b * TT;
    float4 xq = *(const float4*)xp;

    for (int qq = 0; qq < TT / 4; ++qq) {
        const float4 nxt = (qq + 1 < TT / 4) ? *(const float4*)(xp + (qq + 1) * 4)
                                             : make_float4(0.f, 0.f, 0.f, 0.f);
#pragma unroll
        for (int u = 0; u < 4; ++u) {
            const float xt = (u == 0) ? xq.x : (u == 1) ? xq.y
                           : (u == 2) ? xq.z : xq.w;
            f32x4 acc1 = { fmaf(xt, wih1[0], bias1[0]), fmaf(xt, wih1[1], bias1[1]),
                           fmaf(xt, wih1[2], bias1[2]), fmaf(xt, wih1[3], bias1[3]) };
            f32x4 acc2 = { fmaf(xt, wih2[0], bias2[0]), fmaf(xt, wih2[1], bias2[1]),
                           fmaf(xt, wih2[2], bias2[2]), fmaf(xt, wih2[3], bias2[3]) };
            // B fragment = this lane's own h, split hi/lo and packed
            unsigned bh0, bh1, bh2, bh3, bl0, bl1, bl2, bl3;
            BPAIR(h0, h1, bh0, bl0);
            BPAIR(h2, h3, bh1, bl1);
            BPAIR(h4, h5, bh2, bl2);
            BPAIR(h6, h7, bh3, bl3);
            const bf16x8 Bh = __builtin_bit_cast(bf16x8, (uint4v){bh0, bh1, bh2, bh3});
            const bf16x8 Bl = __builtin_bit_cast(bf16x8, (uint4v){bl0, bl1, bl2, bl3});
            // 3-MFMA split-float per tile (lo*lo dropped); same-acc MFMA
            // chaining is the HW-pipelined fast path
            acc1 = __builtin_amdgcn_mfma_f32_16x16x32_bf16(A1h, Bh, acc1, 0, 0, 0);
            acc2 = __builtin_amdgcn_mfma_f32_16x16x32_bf16(A2h, Bh, acc2, 0, 0, 0);
            acc1 = __builtin_amdgcn_mfma_f32_16x16x32_bf16(A1h, Bl, acc1, 0, 0, 0);
            acc2 = __builtin_amdgcn_mfma_f32_16x16x32_bf16(A2h, Bl, acc2, 0, 0, 0);
            acc1 = __builtin_amdgcn_mfma_f32_16x16x32_bf16(A1l, Bh, acc1, 0, 0, 0);
            acc2 = __builtin_amdgcn_mfma_f32_16x16x32_bf16(A2l, Bh, acc2, 0, 0, 0);
            // tanh; rows 30/31 get acc==0 -> exactly 0
            h0 = tanh_fast(acc1[0]); h1 = tanh_fast(acc1[1]);
            h2 = tanh_fast(acc1[2]); h3 = tanh_fast(acc1[3]);
            h4 = tanh_fast(acc2[0]); h5 = tanh_fast(acc2[1]);
            h6 = tanh_fast(acc2[2]); h7 = tanh_fast(acc2[3]);
        }
        xq = nxt;
    }

    // ---- FC head: lane holds h[8g..8g+7]; reduce across the 4 groups ----
    const float hreg[8] = {h0, h1, h2, h3, h4, h5, h6, h7};
#pragma unroll
    for (int c = 0; c < CC; ++c) {
        float p = 0.f;
#pragma unroll
        for (int j = 0; j < 8; ++j) {
            const int k = 8 * g + j;
            if (k < HH) p = fmaf(W_fc[c * HH + k], hreg[j], p);
        }
        p += __shfl_xor(p, 16);
        p += __shfl_xor(p, 32);
        if (g == 0) out[(size_t)b * CC + c] = p + b_fc[c];
    }
}

extern "C" void kernel_launch(void* const* d_in, const int* in_sizes, int n_in,
                              void* d_out, int out_size, void* d_ws, size_t ws_size,
                              hipStream_t stream) {
    const float* x    = (const float*)d_in[0];
    const float* W_ih = (const float*)d_in[1];
    const float* W_hh = (const float*)d_in[2];
    const float* b_ih = (const float*)d_in[3];
    const float* b_hh = (const float*)d_in[4];
    const float* W_fc = (const float*)d_in[5];
    const float* b_fc = (const float*)d_in[6];

    hipLaunchKernelGGL(rnn_scan_kernel,
                       dim3(BB / 128), dim3(512), 0, stream,
                       x, W_ih, W_hh, b_ih, b_hh, W_fc, b_fc,
                       (float*)d_out);
}

// Round 9
// 287.248 us; speedup vs baseline: 1.4055x; 1.4055x over previous
//
#include <hip/hip_runtime.h>

// RNN: h_t = tanh(x_t * W_ih^T + b_ih + h_{t-1} W_hh^T + b_hh), out = h_T W_fc^T + b_fc
// B=8192, T=784, I=1, H=30 (pad 32), C=10. fp32.
//
// R11 = R9 geometry (512 blocks x 64 thr, 1 wave/SIMD on 512 SIMDs -- the
// proven 233us config; R10 showed consolidation trades active SIMDs 2:1 for
// a 1.34x per-SIMD gain and loses) + serial-chain cuts:
//  1. MFMA chain 3-serial -> two parallel chains: P = Whi*Bh (+C-init),
//     Q = Whi*Bl -> Wlo*Bh; h-input = P+Q (vector add). Exposed latency
//     3L -> 2L (+4).
//  2. W_hh/W_ih/bias pre-scaled by 2 (exact: exponent bump; bf16 split
//     residual scales exactly too) => tanh = 1-2*rcp(expf(acc)+1), no
//     leading mul: 8 muls off the serial tail per step.
//  3. x prefetch depth 2 (two float4 in flight).
// Everything else identical to R9: zero-shuffle permuted-A layout (lane's
// D output == its next B fragment), split-float precision (lo*lo dropped),
// volatile pins, no LDS, shfl FC head.
// Wave-step cost is batches-independent (tanh/pack are per-lane), so 16
// batches/wave & 512 waves is forced; the only lever is step latency.

#define BB 8192
#define TT 784
#define HH 30
#define CC 10

typedef __attribute__((ext_vector_type(8))) short  bf16x8;
typedef __attribute__((ext_vector_type(4))) float  f32x4;
typedef __attribute__((ext_vector_type(4))) unsigned uint4v;

__device__ __forceinline__ float tanh_pre(float s) {
    // input s = 2*a ;  tanh(a) = 1 - 2/(e^{2a}+1)
    return 1.0f - 2.0f * __builtin_amdgcn_rcpf(__expf(s) + 1.0f);
}

// (p0,p1) f32 -> packed bf16 pair hp (RNE) + packed bf16 residual pair lp.
#define BPAIR(p0, p1, hp, lp) do {                                          \
    asm("v_cvt_pk_bf16_f32 %0, %1, %2" : "=v"(hp) : "v"(p0), "v"(p1));      \
    const float _h0 = __uint_as_float((hp) << 16);                          \
    const float _h1 = __uint_as_float((hp) & 0xffff0000u);                  \
    const float _l0 = (p0) - _h0;                                           \
    const float _l1 = (p1) - _h1;                                           \
    asm("v_cvt_pk_bf16_f32 %0, %1, %2" : "=v"(lp) : "v"(_l0), "v"(_l1));    \
} while (0)

__global__ __launch_bounds__(64)
__attribute__((amdgpu_waves_per_eu(1, 1)))
void rnn_scan_kernel(const float* __restrict__ x,
                     const float* __restrict__ W_ih,
                     const float* __restrict__ W_hh,
                     const float* __restrict__ b_ih,
                     const float* __restrict__ b_hh,
                     const float* __restrict__ W_fc,
                     const float* __restrict__ b_fc,
                     float* __restrict__ out) {
    const int lane = threadIdx.x & 63;
    const int n    = lane & 15;          // batch column (A row index too)
    const int g    = lane >> 4;          // k-group / D-row group
    const int b    = blockIdx.x * 16 + n;

    // ---- A fragments from W' = 2*W_hh (scale exact) ----
    const int r1 = 8 * (n >> 2) + (n & 3);   // tile1 W-row, always <= 27
    const int r2 = r1 + 4;                    // tile2 W-row, 30/31 -> zero row
    unsigned a1h[4], a1l[4], a2h[4], a2l[4];
#pragma unroll
    for (int d = 0; d < 4; ++d) {
        const int k0 = 8 * g + 2 * d, k1 = k0 + 1;
        const float w1a = (k0 < HH) ? 2.0f * W_hh[r1 * HH + k0] : 0.f;
        const float w1b = (k1 < HH) ? 2.0f * W_hh[r1 * HH + k1] : 0.f;
        const float w2a = (r2 < HH && k0 < HH) ? 2.0f * W_hh[r2 * HH + k0] : 0.f;
        const float w2b = (r2 < HH && k1 < HH) ? 2.0f * W_hh[r2 * HH + k1] : 0.f;
        const unsigned u1a = __float_as_uint(w1a), u1b = __float_as_uint(w1b);
        const unsigned u2a = __float_as_uint(w2a), u2b = __float_as_uint(w2b);
        a1h[d] = (u1b & 0xffff0000u) | (u1a >> 16);
        a2h[d] = (u2b & 0xffff0000u) | (u2a >> 16);
        const float l1a = w1a - __uint_as_float(u1a & 0xffff0000u);
        const float l1b = w1b - __uint_as_float(u1b & 0xffff0000u);
        const float l2a = w2a - __uint_as_float(u2a & 0xffff0000u);
        const float l2b = w2b - __uint_as_float(u2b & 0xffff0000u);
        a1l[d] = (__float_as_uint(l1b) & 0xffff0000u) | (__float_as_uint(l1a) >> 16);
        a2l[d] = (__float_as_uint(l2b) & 0xffff0000u) | (__float_as_uint(l2a) >> 16);
    }
    bf16x8 A1h = __builtin_bit_cast(bf16x8, (uint4v){a1h[0], a1h[1], a1h[2], a1h[3]});
    bf16x8 A1l = __builtin_bit_cast(bf16x8, (uint4v){a1l[0], a1l[1], a1l[2], a1l[3]});
    bf16x8 A2h = __builtin_bit_cast(bf16x8, (uint4v){a2h[0], a2h[1], a2h[2], a2h[3]});
    bf16x8 A2l = __builtin_bit_cast(bf16x8, (uint4v){a2l[0], a2l[1], a2l[2], a2l[3]});
    asm volatile("" : "+v"(A1h), "+v"(A1l), "+v"(A2h), "+v"(A2l));

    // ---- C-init params, pre-scaled by 2 ----
    float bias1[4], wih1[4], bias2[4], wih2[4];
#pragma unroll
    for (int r = 0; r < 4; ++r) {
        const int q1 = 8 * g + r;                       // <= 27
        bias1[r] = 2.0f * (b_ih[q1] + b_hh[q1]);
        wih1[r]  = 2.0f * W_ih[q1];
        const int q2 = q1 + 4;                          // 30/31 -> zero
        bias2[r] = (q2 < HH) ? 2.0f * (b_ih[q2] + b_hh[q2]) : 0.f;
        wih2[r]  = (q2 < HH) ? 2.0f * W_ih[q2] : 0.f;
        asm volatile("" : "+v"(bias1[r]), "+v"(wih1[r]), "+v"(bias2[r]), "+v"(wih2[r]));
    }

    // h state: lane holds h[8g+j], j=0..7 (unscaled)
    float h0 = 0.f, h1 = 0.f, h2 = 0.f, h3 = 0.f;
    float h4 = 0.f, h5 = 0.f, h6 = 0.f, h7 = 0.f;

    const float* xp = x + (size_t)b * TT;
    const int NQ = TT / 4;
    float4 xq = *(const float4*)xp;
    float4 xn = *(const float4*)(xp + 4);

    for (int qq = 0; qq < NQ; ++qq) {
        const float4 xf = (qq + 2 < NQ) ? *(const float4*)(xp + (qq + 2) * 4)
                                        : make_float4(0.f, 0.f, 0.f, 0.f);
#pragma unroll
        for (int u = 0; u < 4; ++u) {
            const float xt = (u == 0) ? xq.x : (u == 1) ? xq.y
                           : (u == 2) ? xq.z : xq.w;
            f32x4 accP1 = { fmaf(xt, wih1[0], bias1[0]), fmaf(xt, wih1[1], bias1[1]),
                            fmaf(xt, wih1[2], bias1[2]), fmaf(xt, wih1[3], bias1[3]) };
            f32x4 accP2 = { fmaf(xt, wih2[0], bias2[0]), fmaf(xt, wih2[1], bias2[1]),
                            fmaf(xt, wih2[2], bias2[2]), fmaf(xt, wih2[3], bias2[3]) };
            // B fragment = this lane's own h, split hi/lo and packed
            unsigned bh0, bh1, bh2, bh3, bl0, bl1, bl2, bl3;
            BPAIR(h0, h1, bh0, bl0);
            BPAIR(h2, h3, bh1, bl1);
            BPAIR(h4, h5, bh2, bl2);
            BPAIR(h6, h7, bh3, bl3);
            const bf16x8 Bh = __builtin_bit_cast(bf16x8, (uint4v){bh0, bh1, bh2, bh3});
            const bf16x8 Bl = __builtin_bit_cast(bf16x8, (uint4v){bl0, bl1, bl2, bl3});
            // two parallel chains per tile: P (1 MFMA, carries C-init),
            // Q (2 MFMAs). Exposed latency 2L instead of 3L.
            const f32x4 zed = {0.f, 0.f, 0.f, 0.f};
            accP1 = __builtin_amdgcn_mfma_f32_16x16x32_bf16(A1h, Bh, accP1, 0, 0, 0);
            accP2 = __builtin_amdgcn_mfma_f32_16x16x32_bf16(A2h, Bh, accP2, 0, 0, 0);
            f32x4 q1 = __builtin_amdgcn_mfma_f32_16x16x32_bf16(A1h, Bl, zed, 0, 0, 0);
            f32x4 q2 = __builtin_amdgcn_mfma_f32_16x16x32_bf16(A2h, Bl, zed, 0, 0, 0);
            q1 = __builtin_amdgcn_mfma_f32_16x16x32_bf16(A1l, Bh, q1, 0, 0, 0);
            q2 = __builtin_amdgcn_mfma_f32_16x16x32_bf16(A2l, Bh, q2, 0, 0, 0);
            const f32x4 s1 = accP1 + q1;
            const f32x4 s2 = accP2 + q2;
            // tanh (input already 2a); rows 30/31 get 0 -> exactly 0
            h0 = tanh_pre(s1[0]); h1 = tanh_pre(s1[1]);
            h2 = tanh_pre(s1[2]); h3 = tanh_pre(s1[3]);
            h4 = tanh_pre(s2[0]); h5 = tanh_pre(s2[1]);
            h6 = tanh_pre(s2[2]); h7 = tanh_pre(s2[3]);
        }
        xq = xn;
        xn = xf;
    }

    // ---- FC head: lane holds h[8g..8g+7]; reduce across the 4 groups ----
    const float hreg[8] = {h0, h1, h2, h3, h4, h5, h6, h7};
#pragma unroll
    for (int c = 0; c < CC; ++c) {
        float p = 0.f;
#pragma unroll
        for (int j = 0; j < 8; ++j) {
            const int k = 8 * g + j;
            if (k < HH) p = fmaf(W_fc[c * HH + k], hreg[j], p);
        }
        p += __shfl_xor(p, 16);
        p += __shfl_xor(p, 32);
        if (g == 0) out[(size_t)b * CC + c] = p + b_fc[c];
    }
}

extern "C" void kernel_launch(void* const* d_in, const int* in_sizes, int n_in,
                              void* d_out, int out_size, void* d_ws, size_t ws_size,
                              hipStream_t stream) {
    const float* x    = (const float*)d_in[0];
    const float* W_ih = (const float*)d_in[1];
    const float* W_hh = (const float*)d_in[2];
    const float* b_ih = (const float*)d_in[3];
    const float* b_hh = (const float*)d_in[4];
    const float* W_fc = (const float*)d_in[5];
    const float* b_fc = (const float*)d_in[6];

    hipLaunchKernelGGL(rnn_scan_kernel,
                       dim3(BB / 16), dim3(64), 0, stream,
                       x, W_ih, W_hh, b_ih, b_hh, W_fc, b_fc,
                       (float*)d_out);
}

// Round 10
// 273.625 us; speedup vs baseline: 1.4755x; 1.0498x over previous
//
#include <hip/hip_runtime.h>

// RNN: h_t = tanh(x_t * W_ih^T + b_ih + h_{t-1} W_hh^T + b_hh), out = h_T W_fc^T + b_fc
// B=8192, T=784, I=1, H=30 (pad 32), C=10. fp32.
//
// R12: two-wave tile split. R11 (+ units fix: VALUBusy is averaged over ALL
// SIMDs; populated-SIMD busy ~68%) showed the wave-step is ISSUE-bound on
// the per-lane serial tail (8 tanh + 4 BPAIR + misc), which is fixed by the
// 2-tiles-per-wave layout and caps the machine at 512 waves / 1024 SIMDs.
// Split: wave 0 owns tile1 (h rows 8g+0..3), wave 1 owns tile2 (8g+4..7).
// -> 4 h/lane tail (halved), 1024 waves (all SIMDs populated).
// Per step each wave packs its own 4 h (split-float bf16 hi+lo, proven
// R9-R11), publishes 16B to LDS, __syncthreads, reads the full 32B packed
// B-fragment (uniform layout [parity][lane][half] -> one b128 per hi/lo),
// then 3 MFMAs (P=Whi*Bh+Cinit; Q=Whi*Bl->Wlo*Bh) + 4 tanh. Double-buffered
// by step parity => ONE barrier/step, no WAR race (writes of step t+1 go to
// the other buffer; reads of t complete before barrier t+1).
// tanh folds 2*log2(e) into W/bias/wih: tanh(a) = 1 - 2/(2^s+1), exp2
// direct (no leading muls). Numerics otherwise identical to R9-R11.

#define BB 8192
#define TT 784
#define HH 30
#define CC 10

typedef __attribute__((ext_vector_type(8))) short  bf16x8;
typedef __attribute__((ext_vector_type(4))) float  f32x4;
typedef __attribute__((ext_vector_type(4))) unsigned uint4v;

#if __has_builtin(__builtin_amdgcn_exp2f)
#define EXP2(v) __builtin_amdgcn_exp2f(v)
#else
#define EXP2(v) __expf((v) * 0.69314718055994531f)   // e^(x ln2) = 2^x
#endif

// pre-scale folded into W_hh/W_ih/bias: 2*log2(e)
#define SCL 2.8853900817779268f

__device__ __forceinline__ float tanh_e2(float s) {
    // s = 2*log2e*a ;  tanh(a) = 1 - 2/(2^s + 1)
    return 1.0f - 2.0f * __builtin_amdgcn_rcpf(EXP2(s) + 1.0f);
}

// (p0,p1) f32 -> packed bf16 pair hp (hi) + packed bf16 residual pair lp.
#define BPAIR(p0, p1, hp, lp) do {                                          \
    asm("v_cvt_pk_bf16_f32 %0, %1, %2" : "=v"(hp) : "v"(p0), "v"(p1));      \
    const float _h0 = __uint_as_float((hp) << 16);                          \
    const float _h1 = __uint_as_float((hp) & 0xffff0000u);                  \
    const float _l0 = (p0) - _h0;                                           \
    const float _l1 = (p1) - _h1;                                           \
    asm("v_cvt_pk_bf16_f32 %0, %1, %2" : "=v"(lp) : "v"(_l0), "v"(_l1));    \
} while (0)

__global__ __launch_bounds__(128)
__attribute__((amdgpu_waves_per_eu(1, 1)))
void rnn_scan_kernel(const float* __restrict__ x,
                     const float* __restrict__ W_ih,
                     const float* __restrict__ W_hh,
                     const float* __restrict__ b_ih,
                     const float* __restrict__ b_hh,
                     const float* __restrict__ W_fc,
                     const float* __restrict__ b_fc,
                     float* __restrict__ out) {
    // [parity][lane][half]: half 0 = h[8g+0..3] (wave0), half 1 = h[8g+4..7].
    // u64 = two packed-bf16-pair u32s. b128 read of [lane][0..1] = B fragment.
    __shared__ unsigned long long Ehi[2][64][2];
    __shared__ unsigned long long Elo[2][64][2];
    __shared__ float hfc[16][33];

    const int tid  = threadIdx.x;
    const int wv   = tid >> 6;        // 0: tile1, 1: tile2
    const int lane = tid & 63;
    const int n    = lane & 15;       // batch column / A-tile row
    const int g    = lane >> 4;       // k-group / D-row group
    const int b    = blockIdx.x * 16 + n;

    // ---- A fragment: tile row n holds W row 8(n>>2)+(n&3)+4wv (permuted
    // so each lane's D output is exactly its next B fragment; proven R9) ----
    const int rr = 8 * (n >> 2) + (n & 3) + 4 * wv;   // 30,31 -> zero rows
    unsigned ah[4], al[4];
#pragma unroll
    for (int d = 0; d < 4; ++d) {
        const int k0 = 8 * g + 2 * d, k1 = k0 + 1;
        const float wa = (rr < HH && k0 < HH) ? SCL * W_hh[rr * HH + k0] : 0.f;
        const float wb = (rr < HH && k1 < HH) ? SCL * W_hh[rr * HH + k1] : 0.f;
        const unsigned ua = __float_as_uint(wa), ub = __float_as_uint(wb);
        ah[d] = (ub & 0xffff0000u) | (ua >> 16);
        const float la = wa - __uint_as_float(ua & 0xffff0000u);
        const float lb = wb - __uint_as_float(ub & 0xffff0000u);
        al[d] = (__float_as_uint(lb) & 0xffff0000u) | (__float_as_uint(la) >> 16);
    }
    bf16x8 Ah = __builtin_bit_cast(bf16x8, (uint4v){ah[0], ah[1], ah[2], ah[3]});
    bf16x8 Al = __builtin_bit_cast(bf16x8, (uint4v){al[0], al[1], al[2], al[3]});
    asm volatile("" : "+v"(Ah), "+v"(Al));

    // ---- C-init params: this lane+wave's D rows are h rows 8g+4wv+r ----
    float bias[4], wih[4];
#pragma unroll
    for (int r = 0; r < 4; ++r) {
        const int q = 8 * g + 4 * wv + r;             // 30,31 -> zero
        bias[r] = (q < HH) ? SCL * (b_ih[q] + b_hh[q]) : 0.f;
        wih[r]  = (q < HH) ? SCL * W_ih[q] : 0.f;
        asm volatile("" : "+v"(bias[r]), "+v"(wih[r]));
    }

    // own h state (4 rows); rows 30/31: acc==0 -> tanh_e2(0)=1-2*rcp(2)=0.
    float h0 = 0.f, h1 = 0.f, h2 = 0.f, h3 = 0.f;

    const float* xp = x + (size_t)b * TT;
    const int NQ = TT / 4;
    float4 xq = *(const float4*)xp;
    float4 xn = *(const float4*)(xp + 4);

    for (int qq = 0; qq < NQ; ++qq) {
        const float4 xf = (qq + 2 < NQ) ? *(const float4*)(xp + (qq + 2) * 4)
                                        : make_float4(0.f, 0.f, 0.f, 0.f);
#pragma unroll
        for (int u = 0; u < 4; ++u) {
            const float xt = (u == 0) ? xq.x : (u == 1) ? xq.y
                           : (u == 2) ? xq.z : xq.w;
            const int buf = u & 1;   // global step parity (4 steps per qq)
            // pack own h(t-1), publish to this parity's buffer
            unsigned hp0, hp1, lp0, lp1;
            BPAIR(h0, h1, hp0, lp0);
            BPAIR(h2, h3, hp1, lp1);
            Ehi[buf][lane][wv] = (unsigned long long)hp0 |
                                 ((unsigned long long)hp1 << 32);
            Elo[buf][lane][wv] = (unsigned long long)lp0 |
                                 ((unsigned long long)lp1 << 32);
            // C-init overlaps the barrier wait
            f32x4 acc = { fmaf(xt, wih[0], bias[0]), fmaf(xt, wih[1], bias[1]),
                          fmaf(xt, wih[2], bias[2]), fmaf(xt, wih[3], bias[3]) };
            __syncthreads();
            const uint4v bhu = *(const uint4v*)&Ehi[buf][lane][0];
            const uint4v blu = *(const uint4v*)&Elo[buf][lane][0];
            const bf16x8 Bh = __builtin_bit_cast(bf16x8, bhu);
            const bf16x8 Bl = __builtin_bit_cast(bf16x8, blu);
            const f32x4 zed = {0.f, 0.f, 0.f, 0.f};
            // P chain (carries C-init) || Q chain; s = P + Q
            acc = __builtin_amdgcn_mfma_f32_16x16x32_bf16(Ah, Bh, acc, 0, 0, 0);
            f32x4 qv = __builtin_amdgcn_mfma_f32_16x16x32_bf16(Ah, Bl, zed, 0, 0, 0);
            qv = __builtin_amdgcn_mfma_f32_16x16x32_bf16(Al, Bh, qv, 0, 0, 0);
            const f32x4 s = acc + qv;
            h0 = tanh_e2(s[0]); h1 = tanh_e2(s[1]);
            h2 = tanh_e2(s[2]); h3 = tanh_e2(s[3]);
        }
        xq = xn;
        xn = xf;
    }

    // ---- FC head: gather full h per batch in LDS, wave 0 computes ----
    hfc[n][8 * g + 4 * wv + 0] = h0;
    hfc[n][8 * g + 4 * wv + 1] = h1;
    hfc[n][8 * g + 4 * wv + 2] = h2;
    hfc[n][8 * g + 4 * wv + 3] = h3;
    __syncthreads();
    if (wv == 0) {
#pragma unroll
        for (int j = 0; j < 3; ++j) {
            const int c = g + 4 * j;          // covers c=0..9 exactly once
            if (c < CC) {
                float acc = b_fc[c];
#pragma unroll
                for (int k = 0; k < HH; ++k)
                    acc = fmaf(W_fc[c * HH + k], hfc[n][k], acc);
                out[(size_t)b * CC + c] = acc;
            }
        }
    }
}

extern "C" void kernel_launch(void* const* d_in, const int* in_sizes, int n_in,
                              void* d_out, int out_size, void* d_ws, size_t ws_size,
                              hipStream_t stream) {
    const float* x    = (const float*)d_in[0];
    const float* W_ih = (const float*)d_in[1];
    const float* W_hh = (const float*)d_in[2];
    const float* b_ih = (const float*)d_in[3];
    const float* b_hh = (const float*)d_in[4];
    const float* W_fc = (const float*)d_in[5];
    const float* b_fc = (const float*)d_in[6];

    hipLaunchKernelGGL(rnn_scan_kernel,
                       dim3(BB / 16), dim3(128), 0, stream,
                       x, W_ih, W_hh, b_ih, b_hh, W_fc, b_fc,
                       (float*)d_out);
}